// Round 7
// baseline (36.449 us; speedup 1.0000x reference)
//
#include <hip/hip_runtime.h>

#define NB 8
#define NN 512
#define DD 64

typedef short bf16x8 __attribute__((ext_vector_type(8)));
typedef float f32x4 __attribute__((ext_vector_type(4)));

__device__ __forceinline__ unsigned short f2bf(float f) {
    unsigned int x = __builtin_bit_cast(unsigned int, f);
    x += 0x7FFFu + ((x >> 16) & 1u);      // round-to-nearest-even (finite inputs)
    return (unsigned short)(x >> 16);
}

// one-hot A-fragment from 8 packed 2-bit fields (low 16 bits); rep = cls*0x5555
__device__ __forceinline__ bf16x8 onehot_packed(unsigned int bits, unsigned int rep) {
    unsigned int x = bits ^ rep;           // field == 0 where class matches
    unsigned int y = x | (x >> 1);
    unsigned int m = ~y & 0x55555555u;     // bit 2i = match_i
    union { unsigned int u[4]; bf16x8 v; } r;
    #pragma unroll
    for (int j = 0; j < 4; ++j) {
        unsigned int f = m >> (4 * j);
        r.u[j] = ((f & 1u) ? 0x3F80u : 0u) | ((f & 4u) ? 0x3F800000u : 0u);
    }
    return r.v;
}

// ---------------- fully fused: ONE dispatch, self-staging blocks ----------------
// block = (b = blk&7 -> XCD-pinned batch, v0 = (blk>>3)*8). 4 waves = (dir, rt).
__global__ __launch_bounds__(256) void msg_fused_kernel(
    const float* __restrict__ h, const int* __restrict__ adj,
    const float* __restrict__ Min, const float* __restrict__ Mout,
    const float* __restrict__ bias, float* __restrict__ out)
{
    __shared__ unsigned short HT[4][DD][128];          // 64 KB swizzled H^T (R6 image)
    __shared__ __align__(16) unsigned int pR[8][32];   // 1 KB row-pack
    __shared__ __align__(16) unsigned int pC[8][32];   // 1 KB col-pack
    __shared__ __align__(16) char scratch[64 * 73 * 2];// 9.3 KB: tile16, later S2 (8 KB)

    unsigned short (*tile16)[73]    = (unsigned short (*)[73])scratch;
    unsigned short (*S2)[8][256]    = (unsigned short (*)[8][256])scratch;

    const int t = threadIdx.x;
    const int lane = t & 63, wv = t >> 6;
    const int dir = wv >> 1, rt = wv & 1;
    const int b  = blockIdx.x & 7;            // XCD-pinned batch (blk%8 ~ XCD id)
    const int v0 = (blockIdx.x >> 3) * 8;
    const int r = lane & 15, kb = lane >> 4;

    const int*   adjb = adj + (size_t)b * NN * NN;
    const float* hb   = h   + (size_t)b * NN * DD;

    // ---- A1: row-pack pR[v][pk] from coalesced int4 row reads ----
    {
        int v = t >> 5, pk = t & 31;
        const int* src = adjb + (size_t)(v0 + v) * NN + pk * 16;
        int4 a0 = *(const int4*)(src + 0),  a1 = *(const int4*)(src + 4);
        int4 a2 = *(const int4*)(src + 8),  a3 = *(const int4*)(src + 12);
        unsigned int u =
            ((unsigned int)a0.x & 3u)        | (((unsigned int)a0.y & 3u) << 2)  |
            (((unsigned int)a0.z & 3u) << 4) | (((unsigned int)a0.w & 3u) << 6)  |
            (((unsigned int)a1.x & 3u) << 8) | (((unsigned int)a1.y & 3u) << 10) |
            (((unsigned int)a1.z & 3u) << 12)| (((unsigned int)a1.w & 3u) << 14) |
            (((unsigned int)a2.x & 3u) << 16)| (((unsigned int)a2.y & 3u) << 18) |
            (((unsigned int)a2.z & 3u) << 20)| (((unsigned int)a2.w & 3u) << 22) |
            (((unsigned int)a3.x & 3u) << 24)| (((unsigned int)a3.y & 3u) << 26) |
            (((unsigned int)a3.z & 3u) << 28)| (((unsigned int)a3.w & 3u) << 30);
        pR[v][pk] = u;
    }

    // ---- A2: col-pack pC[v][pk] via 16-lane shfl_xor OR-butterfly ----
    #pragma unroll
    for (int it = 0; it < 2; ++it) {
        int w = it * 256 + t;
        const int* src = adjb + (size_t)w * NN + v0;   // 32B, 16B-aligned (v0%8==0)
        int4 a0 = *(const int4*)src, a1 = *(const int4*)(src + 4);
        int sh = 2 * (w & 15);                          // bit slot (lanes are w-consecutive)
        #pragma unroll
        for (int v = 0; v < 8; ++v) {
            int av = (v==0)?a0.x:(v==1)?a0.y:(v==2)?a0.z:(v==3)?a0.w:
                     (v==4)?a1.x:(v==5)?a1.y:(v==6)?a1.z:a1.w;
            unsigned int u = ((unsigned int)av & 3u) << sh;
            u |= __shfl_xor(u, 1);  u |= __shfl_xor(u, 2);
            u |= __shfl_xor(u, 4);  u |= __shfl_xor(u, 8);   // all 16 lanes hold OR
            if ((t & 15) == v) pC[v][w >> 4] = u;
        }
    }

    // ---- A3: h -> HT (bf16, swizzled R6 image), 8 passes via padded tile16 ----
    for (int p = 0; p < 8; ++p) {
        int w0 = p * 64;
        #pragma unroll
        for (int i = 0; i < 4; ++i) {                  // coalesced f32 loads
            int idx = i * 256 + t, w = idx >> 4, eq = idx & 15;
            float4 f = *(const float4*)&hb[(size_t)(w0 + w) * DD + eq * 4];
            unsigned int lo = f2bf(f.x) | ((unsigned int)f2bf(f.y) << 16);
            unsigned int hi = f2bf(f.z) | ((unsigned int)f2bf(f.w) << 16);
            *(unsigned int*)&tile16[w][eq * 4]     = lo;
            *(unsigned int*)&tile16[w][eq * 4 + 2] = hi;
        }
        __syncthreads();
        #pragma unroll
        for (int i = 0; i < 8; ++i) {                  // transposed swizzled u32 writes
            int e = 8 * i + (t >> 5), wl = t & 31;
            int wg = 2 * wl;
            unsigned int lo = tile16[wg][e], hi = tile16[wg + 1][e];
            int wglob  = w0 + wg;
            int wchunk = wglob >> 7, wloc = wglob & 127;
            int byte = ((((wloc >> 3) ^ (e & 7)) & 15) << 4) + (wloc & 7) * 2;
            *(unsigned int*)((char*)&HT[wchunk][e][0] + byte) = lo | (hi << 16);
        }
        __syncthreads();
    }
    // (pR/pC writes ordered by the first barrier above; tile16 dead from here)

    // ---- phase 1: S[(v,c),e] = sum_w onehot * h — verified R6 MFMA core ----
    const int vloc = rt * 4 + (r >> 2);
    const unsigned int rep = (unsigned int)(r & 3) * 0x55555555u;
    const unsigned short* prowu =
        (const unsigned short*)(dir ? &pC[vloc][0] : &pR[vloc][0]);

    f32x4 acc[4] = {f32x4{0,0,0,0}, f32x4{0,0,0,0}, f32x4{0,0,0,0}, f32x4{0,0,0,0}};
    #pragma unroll
    for (int c = 0; c < 4; ++c) {
        #pragma unroll
        for (int kc = 0; kc < 4; ++kc) {
            unsigned int bits = prowu[4 * (c * 4 + kc) + kb];   // broadcast u16 read
            bf16x8 afrag = onehot_packed(bits, rep);
            #pragma unroll
            for (int n = 0; n < 4; ++n) {
                int e = n * 16 + r;
                int boff = (kc * 64 + (kb << 4)) ^ ((e & 7) << 4);
                bf16x8 bfrag = *(const bf16x8*)((const char*)&HT[c][e][0] + boff);
                acc[n] = __builtin_amdgcn_mfma_f32_16x16x32_bf16(afrag, bfrag, acc[n], 0, 0, 0);
            }
        }
    }

    // ---- S -> LDS (bf16, XOR-swizzled rows), scratch now reused as S2 ----
    #pragma unroll
    for (int ct = 0; ct < 4; ++ct) {
        #pragma unroll
        for (int rg = 0; rg < 4; ++rg) {
            int row_g = rt * 16 + kb * 4 + rg;        // 0..31 = (v,c)
            int vv = row_g >> 2, cc2 = row_g & 3;
            int e = ct * 16 + r;
            int rb = (cc2 * 128 + e * 2) ^ ((vv & 7) << 4);
            *(unsigned short*)((char*)&S2[dir][vv][0] + rb) = f2bf(acc[ct][rg]);
        }
    }
    __syncthreads();

    // ---- phase 2: msg = S * W, W-fragments direct from global f32 (L2-hot) ----
    const float* Mrow = dir ? Mout : Min;
    f32x4 acc2[2] = {f32x4{0,0,0,0}, f32x4{0,0,0,0}};
    #pragma unroll
    for (int kc = 0; kc < 8; ++kc) {
        int vv = r & 7;                               // A rows 8..15 duplicate 0..7
        int kbase = kc * 32 + kb * 8;
        int rb = (kbase * 2) ^ (vv << 4);
        bf16x8 a2 = *(const bf16x8*)((const char*)&S2[dir][vv][0] + rb);
        #pragma unroll
        for (int j = 0; j < 2; ++j) {
            int d = (rt * 2 + j) * 16 + r;
            const float* wsrc = &Mrow[((size_t)(kbase >> 6) * DD + d) * DD + (kbase & 63)];
            float4 f0 = *(const float4*)wsrc;
            float4 f1 = *(const float4*)(wsrc + 4);
            union { unsigned int u[4]; bf16x8 v; } b2;
            b2.u[0] = f2bf(f0.x) | ((unsigned int)f2bf(f0.y) << 16);
            b2.u[1] = f2bf(f0.z) | ((unsigned int)f2bf(f0.w) << 16);
            b2.u[2] = f2bf(f1.x) | ((unsigned int)f2bf(f1.y) << 16);
            b2.u[3] = f2bf(f1.z) | ((unsigned int)f2bf(f1.w) << 16);
            acc2[j] = __builtin_amdgcn_mfma_f32_16x16x32_bf16(a2, b2.v, acc2[j], 0, 0, 0);
        }
    }
    #pragma unroll
    for (int j = 0; j < 2; ++j) {
        int d = (rt * 2 + j) * 16 + r;
        float bs = bias[dir * DD + d];
        #pragma unroll
        for (int rg = 0; rg < 4; ++rg) {
            int row = kb * 4 + rg;                    // duplicated rows >=8 skipped
            if (row < 8)
                out[((size_t)(b * NN + v0 + row)) * (2 * DD) + dir * DD + d] = acc2[j][rg] + bs;
        }
    }
}

extern "C" void kernel_launch(void* const* d_in, const int* in_sizes, int n_in,
                              void* d_out, int out_size, void* d_ws, size_t ws_size,
                              hipStream_t stream) {
    const float* node_state = (const float*)d_in[0];
    const int*   adj_mat    = (const int*)  d_in[1];
    const float* matrix_in  = (const float*)d_in[2];
    const float* matrix_out = (const float*)d_in[3];
    const float* bias       = (const float*)d_in[4];
    float* out = (float*)d_out;

    msg_fused_kernel<<<NB * NN / 8, 256, 0, stream>>>(
        node_state, adj_mat, matrix_in, matrix_out, bias, out);
}